// Round 18
// baseline (153.148 us; speedup 1.0000x reference)
//
#include <hip/hip_runtime.h>
#include <hip/hip_bf16.h>
#include <cstdint>
#include <cstddef>

#define NP 20000
#define NA 10000
#define NEDGE 100000
#define NEG_INF (-__builtin_huge_valf())
#define INV_SQRT_DK 0.17677669529663687f
#define NPPAD 20096
#define NAPAD 10112
#define GEB 391            // ceil(NEDGE/256)
#define MAXDEG 64

typedef __bf16 bf16_t;
typedef __attribute__((ext_vector_type(8))) short s16x8;
typedef __attribute__((ext_vector_type(4))) float f32x4;
typedef __attribute__((ext_vector_type(4))) __bf16 bf16x4;
typedef __attribute__((ext_vector_type(8))) __bf16 bf16x8v;

union B16 { uint4 u; s16x8 s; bf16x8v b; };

typedef const __attribute__((address_space(1))) void* gas1p;
typedef __attribute__((address_space(3))) void* las3p;
#define GLD16(g, l) __builtin_amdgcn_global_load_lds((gas1p)(g), (las3p)(l), 16, 0, 0)

// ---------- prelude: f2b x4 + weight prep x10 + one-pass bucket scatter ----------
__global__ __launch_bounds__(256) void prelude(
    const float* __restrict__ h_paper, const float* __restrict__ h_author,
    const float* __restrict__ t_paper, const float* __restrict__ t_author,
    bf16_t* __restrict__ Xhp, bf16_t* __restrict__ Xha,
    bf16_t* __restrict__ Xtp, bf16_t* __restrict__ Xta,
    const float* __restrict__ k_w, const float* __restrict__ k_b,
    const float* __restrict__ v_w, const float* __restrict__ v_b,
    const float* __restrict__ q_w, const float* __restrict__ a_w,
    const float* __restrict__ rel_att, const float* __restrict__ rel_msg,
    bf16_t* __restrict__ WT_hp, float* __restrict__ Bhp,
    bf16_t* __restrict__ WT_ha, float* __restrict__ Bha,
    bf16_t* __restrict__ WT_q0, bf16_t* __restrict__ WT_q1,
    bf16_t* __restrict__ WT_a0, bf16_t* __restrict__ WT_a1,
    const int* __restrict__ src0, const int* __restrict__ dst0,
    const int* __restrict__ src1, const int* __restrict__ dst1,
    const int* __restrict__ src2, const int* __restrict__ dst2,
    int* __restrict__ cnt,
    int* __restrict__ sr0, int* __restrict__ sr1, int* __restrict__ sr2)
{
    const int b = blockIdx.x;
    const int t = threadIdx.x;
    if (b < 7500) {
        const float* s; bf16_t* d; int n; int bb;
        if (b < 2500)      { s = h_paper;  d = Xhp; n = NP * 32; bb = b; }
        else if (b < 3750) { s = h_author; d = Xha; n = NA * 32; bb = b - 2500; }
        else if (b < 6250) { s = t_paper;  d = Xtp; n = NP * 32; bb = b - 3750; }
        else               { s = t_author; d = Xta; n = NA * 32; bb = b - 6250; }
        int i = bb * 256 + t;
        if (i >= n) return;
        const float* sp = s + (size_t)i * 8;
        float4 x0 = *(const float4*)sp;
        float4 x1 = *(const float4*)(sp + 4);
        B16 o;
        o.b[0] = (__bf16)x0.x; o.b[1] = (__bf16)x0.y; o.b[2] = (__bf16)x0.z; o.b[3] = (__bf16)x0.w;
        o.b[4] = (__bf16)x1.x; o.b[5] = (__bf16)x1.y; o.b[6] = (__bf16)x1.z; o.b[7] = (__bf16)x1.w;
        *(uint4*)(d + (size_t)i * 8) = o.u;
        return;
    }
    if (b >= 10060) {
        const int cb = b - 10060;
        const int et = cb / GEB, bb = cb % GEB;
        const int e = bb * 256 + t;
        if (e >= NEDGE) return;
        const int *src, *dst; int *c, *srs;
        switch (et) {
            case 0: src = src0; dst = dst0; c = cnt;         srs = sr0; break;
            case 1: src = src1; dst = dst1; c = cnt + 20000; srs = sr1; break;
            default: src = src2; dst = dst2; c = cnt + 40000; srs = sr2;
        }
        const int d = dst[e];
        const int pos = atomicAdd(c + d, 1);
        if (pos < MAXDEG) srs[d * MAXDEG + pos] = src[e];
        return;
    }
    const int j = (b - 7500) >> 8;       // weight job 0..9
    const int c = (b - 7500) & 255;      // output column
    if (j < 6) {
        const float *W, *bi, *R; bf16_t* WT; float* bias; int off, kv;
        switch (j) {
            case 0: W = k_w;         bi = k_b;       R = rel_att + 8192;  WT = WT_hp; bias = Bhp; off = 0;   kv = 0; break;
            case 1: W = v_w;         bi = v_b;       R = rel_msg + 8192;  WT = WT_hp; bias = Bhp; off = 0;   kv = 4; break;
            case 2: W = k_w;         bi = k_b;       R = rel_att + 16384; WT = WT_hp; bias = Bhp; off = 512; kv = 0; break;
            case 3: W = v_w;         bi = v_b;       R = rel_msg + 16384; WT = WT_hp; bias = Bhp; off = 512; kv = 4; break;
            case 4: W = k_w + 65536; bi = k_b + 256; R = rel_att;         WT = WT_ha; bias = Bha; off = 0;   kv = 0; break;
            default:W = v_w + 65536; bi = v_b + 256; R = rel_msg;         WT = WT_ha; bias = Bha; off = 0;   kv = 4;
        }
        __shared__ float rs[32];
        const int h = c >> 5, e = c & 31;
        if (t < 32) rs[t] = R[(h * 32 + t) * 32 + e];
        __syncthreads();
        float s = 0.f;
#pragma unroll
        for (int d = 0; d < 32; ++d) s += W[t * 256 + h * 32 + d] * rs[d];
        const int newc = off + (c >> 2) * 8 + kv + (c & 3);
        WT[newc * 256 + t] = (bf16_t)s;
        if (t == 0) {
            float sb = 0.f;
#pragma unroll
            for (int d = 0; d < 32; ++d) sb += bi[h * 32 + d] * rs[d];
            bias[newc] = sb;
        }
    } else {
        const float* W; bf16_t* WT;
        switch (j) { case 6: W = q_w; WT = WT_q0; break;
                     case 7: W = q_w + 65536; WT = WT_q1; break;
                     case 8: W = a_w; WT = WT_a0; break;
                     default: W = a_w + 65536; WT = WT_a1; }
        WT[c * 256 + t] = (bf16_t)W[t * 256 + c];
    }
}

// ---------- 128x128-tile segmented bf16 MFMA GEMM, 2-phase pipelined (T3) ----------
struct GSeg {
    const bf16_t* X; const bf16_t* WT; const float* bias; void* Y;
    int M, ncb, ldY, blk0;
};
struct GSegs { GSeg s[4]; int n; };

__global__ __launch_bounds__(256) void gemm_seg(GSegs segs)
{
    int si = 0;
#pragma unroll
    for (int i = 1; i < 4; ++i)
        if (i < segs.n && (int)blockIdx.x >= segs.s[i].blk0) si = i;
    const GSeg g = segs.s[si];
    const int lid = blockIdx.x - g.blk0;
    const int nrb = (g.M + 127) >> 7;
    const int c8 = lid & 7;
    const int rest = lid >> 3;
    const int by = rest % g.ncb;
    const int bx = (rest / g.ncb) * 8 + c8;
    if (bx >= nrb) return;
    const int row0 = bx * 128, col0 = by * 128;
    const int M = g.M, ldY = g.ldY;

    union SM {
        uint4 ab[2][1024];          // [buf][A 0..511 | B 512..1023], 32 KB
        ushort epi[4][16][72];
    };
    __shared__ SM sm;
    const int t = threadIdx.x;
    const int w = t >> 6, l = t & 63;
    const int wm = w >> 1, wn = w & 1;
    const int lr = l & 15, ks4 = l >> 4;

    const bf16_t* gA[2]; const bf16_t* gB[2];
    int dA[2], dB[2];
#pragma unroll
    for (int c = 0; c < 2; ++c) {
        const int idx = w * 128 + c * 64 + l;
        const int r = idx >> 2;
        const int s = (idx & 3) ^ ((r >> 1) & 3);
        gA[c] = g.X  + (size_t)(row0 + r) * 256 + s * 8;
        gB[c] = g.WT + (size_t)(col0 + r) * 256 + s * 8;
        dA[c] = w * 128 + c * 64;          // wave-uniform LDS word base
        dB[c] = 512 + w * 128 + c * 64;
    }

    auto STAGE = [&](int buf, int kk) {
        GLD16(gA[0] + kk * 32, sm.ab[buf] + dA[0]);
        GLD16(gB[0] + kk * 32, sm.ab[buf] + dB[0]);
        GLD16(gA[1] + kk * 32, sm.ab[buf] + dA[1]);
        GLD16(gB[1] + kk * 32, sm.ab[buf] + dB[1]);
    };

    f32x4 acc[4][4] = {};
    STAGE(0, 0);
    __syncthreads();
#pragma unroll
    for (int kk = 0; kk < 8; ++kk) {
        const int cur = kk & 1;
        if (kk < 7) STAGE(cur ^ 1, kk + 1);   // prefetch next K-step into other buffer
        B16 af[4], bfr[4];
#pragma unroll
        for (int i = 0; i < 4; ++i) {
            const int ra = wm * 64 + i * 16 + lr;
            af[i].u = sm.ab[cur][ra * 4 + (ks4 ^ ((ra >> 1) & 3))];
            const int rb = wn * 64 + i * 16 + lr;
            bfr[i].u = sm.ab[cur][512 + rb * 4 + (ks4 ^ ((rb >> 1) & 3))];
        }
#pragma unroll
        for (int i = 0; i < 4; ++i)
#pragma unroll
            for (int jn = 0; jn < 4; ++jn)
                acc[i][jn] = __builtin_amdgcn_mfma_f32_16x16x32_bf16(af[i].s, bfr[jn].s, acc[i][jn], 0, 0, 0);
        __syncthreads();   // drains vmcnt: next buffer ready; all reads of cur done
    }

    const int er = l >> 2, ec = (l & 3) * 8;
#pragma unroll
    for (int i = 0; i < 4; ++i) {
        if (i) __syncthreads();
#pragma unroll
        for (int jn = 0; jn < 4; ++jn) {
            const float bv = g.bias[col0 + wn * 64 + jn * 16 + lr];
#pragma unroll
            for (int r = 0; r < 4; ++r) {
                union { ushort u; __bf16 b; } cv;
                cv.b = (__bf16)(acc[i][jn][r] + bv);
                sm.epi[w][ks4 * 4 + r][jn * 16 + lr] = cv.u;
            }
        }
        __syncthreads();
        const int grow = row0 + wm * 64 + i * 16 + er;
        if (grow < M) {
            uint4 v0 = *(const uint4*)&sm.epi[w][er][ec];
            uint4 v1 = *(const uint4*)&sm.epi[w][er][ec + 32];
            bf16_t* yp = (bf16_t*)g.Y + (size_t)grow * ldY + col0 + wn * 64;
            *(uint4*)(yp + ec) = v0;
            *(uint4*)(yp + ec + 32) = v1;
        }
    }
}

// ---------- fused out-GEMM + skip + LayerNorm: 64x256 tile, 2-phase pipelined ----------
struct OSeg { const bf16_t* X; const float* bias; float* Y; const bf16_t* T; int M, blk0, nt; };

__global__ __launch_bounds__(256) void gemm_out_ln(
    OSeg s0, OSeg s1, const bf16_t* __restrict__ WT0, const bf16_t* __restrict__ WT1,
    const float* __restrict__ skip, const float* __restrict__ lns,
    const float* __restrict__ lnb)
{
    const bool second = (int)blockIdx.x >= s1.blk0;
    const OSeg g = second ? s1 : s0;
    const bf16_t* __restrict__ WT = second ? WT1 : WT0;
    const int row0 = ((int)blockIdx.x - g.blk0) * 64;

    union SM {
        uint4 ab[2][1280];  // [buf][A 0..255 | B 256..1279], 40 KB
        struct { ushort epi[4][16][72]; float2 part[16][4]; } e;
    };
    __shared__ SM sm;
    const int t = threadIdx.x;
    const int w = t >> 6, l = t & 63;
    const int lr = l & 15, ks4 = l >> 4;

    const bf16_t* gA; int dAo;
    const bf16_t* gB[4]; int dBo[4];
    {
        const int idx = w * 64 + l;
        const int r = idx >> 2;
        const int s = (idx & 3) ^ ((r >> 1) & 3);
        gA = g.X + (size_t)(row0 + r) * 256 + s * 8;
        dAo = w * 64;
    }
#pragma unroll
    for (int c = 0; c < 4; ++c) {
        const int idx = w * 256 + c * 64 + l;
        const int r = idx >> 2;
        const int s = (idx & 3) ^ ((r >> 1) & 3);
        gB[c] = WT + (size_t)r * 256 + s * 8;
        dBo[c] = 256 + w * 256 + c * 64;
    }

    auto STAGE = [&](int buf, int kk) {
        GLD16(gA + kk * 32, sm.ab[buf] + dAo);
        GLD16(gB[0] + kk * 32, sm.ab[buf] + dBo[0]);
        GLD16(gB[1] + kk * 32, sm.ab[buf] + dBo[1]);
        GLD16(gB[2] + kk * 32, sm.ab[buf] + dBo[2]);
        GLD16(gB[3] + kk * 32, sm.ab[buf] + dBo[3]);
    };

    f32x4 acc[4][4] = {};
    STAGE(0, 0);
    __syncthreads();
#pragma unroll
    for (int kk = 0; kk < 8; ++kk) {
        const int cur = kk & 1;
        if (kk < 7) STAGE(cur ^ 1, kk + 1);
        B16 af[4], bfr[4];
#pragma unroll
        for (int i = 0; i < 4; ++i) {
            const int ra = i * 16 + lr;
            af[i].u = sm.ab[cur][ra * 4 + (ks4 ^ ((ra >> 1) & 3))];
            const int rb = w * 64 + i * 16 + lr;
            bfr[i].u = sm.ab[cur][256 + rb * 4 + (ks4 ^ ((rb >> 1) & 3))];
        }
#pragma unroll
        for (int i = 0; i < 4; ++i)
#pragma unroll
            for (int jn = 0; jn < 4; ++jn)
                acc[i][jn] = __builtin_amdgcn_mfma_f32_16x16x32_bf16(af[i].s, bfr[jn].s, acc[i][jn], 0, 0, 0);
        __syncthreads();
    }

    const float alpha = 1.f / (1.f + __expf(-skip[g.nt]));
    const float beta = 1.f - alpha;
    const int er = l >> 2, cb = (l & 3) * 16;
#pragma unroll
    for (int i = 0; i < 4; ++i) {
#pragma unroll
        for (int jn = 0; jn < 4; ++jn) {
            const float bv = g.bias[w * 64 + jn * 16 + lr];
#pragma unroll
            for (int r = 0; r < 4; ++r) {
                union { ushort u; __bf16 b; } cv;
                cv.b = (__bf16)(acc[i][jn][r] + bv);
                sm.e.epi[w][ks4 * 4 + r][jn * 16 + lr] = cv.u;
            }
        }
        const int grow = row0 + i * 16 + er;
        float v[16];
        {
            const bf16_t* tp = g.T + (size_t)grow * 256 + w * 64 + cb;
            B16 ov0, ov1, tv0, tv1;
            ov0.u = *(const uint4*)&sm.e.epi[w][er][cb];
            ov1.u = *(const uint4*)&sm.e.epi[w][er][cb + 8];
            tv0.u = *(const uint4*)(tp);
            tv1.u = *(const uint4*)(tp + 8);
#pragma unroll
            for (int q = 0; q < 8; ++q) {
                v[q]     = (float)ov0.b[q] * alpha + (float)tv0.b[q] * beta;
                v[8 + q] = (float)ov1.b[q] * alpha + (float)tv1.b[q] * beta;
            }
        }
        float s1 = 0.f, s2 = 0.f;
#pragma unroll
        for (int q = 0; q < 16; ++q) { s1 += v[q]; s2 += v[q] * v[q]; }
        s1 += __shfl_xor(s1, 1, 64); s2 += __shfl_xor(s2, 1, 64);
        s1 += __shfl_xor(s1, 2, 64); s2 += __shfl_xor(s2, 2, 64);
        if ((l & 3) == 0) sm.e.part[er][w] = make_float2(s1, s2);
        __syncthreads();
        float ts1 = 0.f, ts2 = 0.f;
#pragma unroll
        for (int q = 0; q < 4; ++q) { float2 p = sm.e.part[er][q]; ts1 += p.x; ts2 += p.y; }
        const float mean = ts1 * (1.f / 256.f);
        const float var = ts2 * (1.f / 256.f) - mean * mean;
        const float rstd = rsqrtf(var + 1e-5f);
        if (grow < g.M) {
            const int colb = w * 64 + cb;
            const float* ls = lns + g.nt * 256 + colb;
            const float* lb = lnb + g.nt * 256 + colb;
            float* op = g.Y + (size_t)grow * 256 + colb;
#pragma unroll
            for (int q = 0; q < 16; q += 4) {
                float4 o4;
                o4.x = (v[q + 0] - mean) * rstd * ls[q + 0] + lb[q + 0];
                o4.y = (v[q + 1] - mean) * rstd * ls[q + 1] + lb[q + 1];
                o4.z = (v[q + 2] - mean) * rstd * ls[q + 2] + lb[q + 2];
                o4.w = (v[q + 3] - mean) * rstd * ls[q + 3] + lb[q + 3];
                *(float4*)(op + q) = o4;
            }
        }
        __syncthreads();
    }
}

// ---------- per-node online-softmax aggregation (bucketed lists, wave per list) ----------
__device__ __forceinline__ float4 ldb4(const bf16_t* p) {
    bf16x4 v = *(const bf16x4*)p;
    return make_float4((float)v[0], (float)v[1], (float)v[2], (float)v[3]);
}

__device__ __forceinline__ void upd(float& m, float& den, float4& acc,
                                    float score, const float4& v) {
    const float nm = fmaxf(m, score);
    const float r = __expf(m - nm);
    const float p = __expf(score - nm);
    den = den * r + p;
    acc.x = acc.x * r + v.x * p;
    acc.y = acc.y * r + v.y * p;
    acc.z = acc.z * r + v.z * p;
    acc.w = acc.w * r + v.w * p;
    m = nm;
}

__device__ __forceinline__ void step_kv(float& m, float& den, float4& acc,
                                        uint4 kvu, float scale, const float4& q) {
    B16 kv; kv.u = kvu;
    float d = q.x * (float)kv.b[0] + q.y * (float)kv.b[1]
            + q.z * (float)kv.b[2] + q.w * (float)kv.b[3];
    d += __shfl_xor(d, 1, 64);
    d += __shfl_xor(d, 2, 64);
    d += __shfl_xor(d, 4, 64);
    const float4 v = make_float4((float)kv.b[4], (float)kv.b[5],
                                 (float)kv.b[6], (float)kv.b[7]);
    upd(m, den, acc, d * scale, v);
}

__device__ __forceinline__ void aggr_chain(
    const bf16_t* __restrict__ KV, int ld,
    const int* __restrict__ srcs, int deg,
    float scaleH, int lane, const float4& q, float4& res)
{
    res = make_float4(0.f, 0.f, 0.f, 0.f);
    if (deg <= 0) return;
    float m = NEG_INF, den = 0.f;
    float4 acc = make_float4(0.f, 0.f, 0.f, 0.f);
    uint4 kv0 = *(const uint4*)(KV + (size_t)srcs[0] * ld + lane * 8);
    uint4 kv1 = (1 < deg) ? *(const uint4*)(KV + (size_t)srcs[1] * ld + lane * 8) : kv0;
    for (int i = 0; i < deg; ++i) {
        uint4 nx = (i + 2 < deg) ? *(const uint4*)(KV + (size_t)srcs[i + 2] * ld + lane * 8) : kv1;
        step_kv(m, den, acc, kv0, scaleH, q);
        kv0 = kv1; kv1 = nx;
    }
    const float inv = 1.f / den;
    res = make_float4(acc.x * inv, acc.y * inv, acc.z * inv, acc.w * inv);
}

__global__ __launch_bounds__(128) void node_aggr(
    const bf16_t* __restrict__ Qp, const bf16_t* __restrict__ Qa,
    const bf16_t* __restrict__ Yhp, const bf16_t* __restrict__ Yha,
    const int* __restrict__ cnt,
    const int* __restrict__ sr0, const int* __restrict__ sr1, const int* __restrict__ sr2,
    const float* __restrict__ rel_pri, bf16_t* __restrict__ MUb)
{
    __shared__ float4 part[64];
    const int t = threadIdx.x;
    const int wv = t >> 6, lane = t & 63;
    const int h = lane >> 3;
    const int b = blockIdx.x;
    if (b < NP) {
        const int node = b;
        const float4 q = ldb4(Qp + (size_t)node * 256 + lane * 4);
        float4 res;
        if (wv == 0)
            aggr_chain(Yha, 512,  sr0 + (size_t)node * MAXDEG, cnt[node],
                       rel_pri[h] * INV_SQRT_DK, lane, q, res);
        else
            aggr_chain(Yhp, 1024, sr1 + (size_t)node * MAXDEG, cnt[20000 + node],
                       rel_pri[8 + h] * INV_SQRT_DK, lane, q, res);
        if (wv == 1) part[lane] = res;
        __syncthreads();
        if (wv == 0) {
            const float4 c = part[lane];
            bf16x4 o;
            o[0] = (__bf16)((res.x + c.x) * 0.5f);
            o[1] = (__bf16)((res.y + c.y) * 0.5f);
            o[2] = (__bf16)((res.z + c.z) * 0.5f);
            o[3] = (__bf16)((res.w + c.w) * 0.5f);
            *(bf16x4*)(MUb + (size_t)node * 256 + lane * 4) = o;
        }
    } else {
        const int node2 = (b - NP) * 2 + wv;   // author index
        if (node2 >= NA) return;
        const float4 q = ldb4(Qa + (size_t)node2 * 256 + lane * 4);
        float4 res;
        aggr_chain(Yhp + 512, 1024, sr2 + (size_t)node2 * MAXDEG, cnt[40000 + node2],
                   rel_pri[16 + h] * INV_SQRT_DK, lane, q, res);
        bf16x4 o;
        o[0] = (__bf16)res.x; o[1] = (__bf16)res.y;
        o[2] = (__bf16)res.z; o[3] = (__bf16)res.w;
        *(bf16x4*)(MUb + (size_t)(NP + node2) * 256 + lane * 4) = o;
    }
}

extern "C" void kernel_launch(void* const* d_in, const int* in_sizes, int n_in,
                              void* d_out, int out_size, void* d_ws, size_t ws_size,
                              hipStream_t stream) {
    const float* h_paper  = (const float*)d_in[0];
    const float* h_author = (const float*)d_in[1];
    const float* t_paper  = (const float*)d_in[2];
    const float* t_author = (const float*)d_in[3];
    const float* k_w = (const float*)d_in[4];
    const float* k_b = (const float*)d_in[5];
    const float* q_w = (const float*)d_in[6];
    const float* q_b = (const float*)d_in[7];
    const float* v_w = (const float*)d_in[8];
    const float* v_b = (const float*)d_in[9];
    const float* a_w = (const float*)d_in[10];
    const float* a_b = (const float*)d_in[11];
    const float* rel_pri = (const float*)d_in[12];
    const float* rel_att = (const float*)d_in[13];
    const float* rel_msg = (const float*)d_in[14];
    const float* skip = (const float*)d_in[15];
    const float* ln_s = (const float*)d_in[16];
    const float* ln_b = (const float*)d_in[17];
    const int* src0 = (const int*)d_in[18];
    const int* dst0 = (const int*)d_in[19];
    const int* src1 = (const int*)d_in[20];
    const int* dst1 = (const int*)d_in[21];
    const int* src2 = (const int*)d_in[22];
    const int* dst2 = (const int*)d_in[23];

    // ---- workspace layout ----
    char* base = (char*)d_ws;
    size_t off = 0;
    auto alloc = [&](size_t bytes) { char* p = base + off; off += (bytes + 255) & ~(size_t)255; return p; };
    bf16_t* Xhp  = (bf16_t*)alloc((size_t)NPPAD * 256 * 2);
    bf16_t* Xha  = (bf16_t*)alloc((size_t)NAPAD * 256 * 2);
    bf16_t* Xtp  = (bf16_t*)alloc((size_t)NPPAD * 256 * 2);
    bf16_t* Xta  = (bf16_t*)alloc((size_t)NAPAD * 256 * 2);
    bf16_t* Yhp  = (bf16_t*)alloc((size_t)NP * 1024 * 2);  // [KV1 | KV2] interleaved
    bf16_t* Yha  = (bf16_t*)alloc((size_t)NA * 512 * 2);   // [KV0] interleaved
    bf16_t* Qp   = (bf16_t*)alloc((size_t)NP * 256 * 2);
    bf16_t* Qa   = (bf16_t*)alloc((size_t)NA * 256 * 2);
    bf16_t* MUb  = (bf16_t*)alloc((size_t)(NP + NAPAD) * 256 * 2);
    bf16_t* WT_hp = (bf16_t*)alloc(1024 * 256 * 2);
    bf16_t* WT_ha = (bf16_t*)alloc(512 * 256 * 2);
    bf16_t* WT_q0 = (bf16_t*)alloc(256 * 256 * 2);
    bf16_t* WT_q1 = (bf16_t*)alloc(256 * 256 * 2);
    bf16_t* WT_a0 = (bf16_t*)alloc(256 * 256 * 2);
    bf16_t* WT_a1 = (bf16_t*)alloc(256 * 256 * 2);
    float* Bhp = (float*)alloc(1024 * 4);
    float* Bha = (float*)alloc(512 * 4);
    int* cnt0 = (int*)alloc(50000 * 4);   // cnt0[20000] | cnt1[20000] | cnt2[10000]
    int* sr0 = (int*)alloc((size_t)NP * MAXDEG * 4);
    int* sr1 = (int*)alloc((size_t)NP * MAXDEG * 4);
    int* sr2 = (int*)alloc((size_t)NA * MAXDEG * 4);

    // ---- zero counts (async memset, graph-capture legal) ----
    hipMemsetAsync(cnt0, 0, 50000 * sizeof(int), stream);

    // ---- prelude: f2b + weight prep + one-pass bucket scatter ----
    prelude<<<10060 + 3 * GEB, 256, 0, stream>>>(
        h_paper, h_author, t_paper, t_author, Xhp, Xha, Xtp, Xta,
        k_w, k_b, v_w, v_b, q_w, a_w, rel_att, rel_msg,
        WT_hp, Bhp, WT_ha, Bha, WT_q0, WT_q1, WT_a0, WT_a1,
        src0, dst0, src1, dst1, src2, dst2, cnt0, sr0, sr1, sr2);

    // ---- projections (4 segments, XCD-pinned col-tiles, 2-phase pipelined) ----
    GSegs P{};
    P.s[0] = { Xhp, WT_hp, Bhp,       Yhp, NP, 8, 1024, 0 };
    P.s[1] = { Xha, WT_ha, Bha,       Yha, NA, 4, 512,  1280 };
    P.s[2] = { Xtp, WT_q0, q_b,       Qp,  NP, 2, 256,  1600 };
    P.s[3] = { Xta, WT_q1, q_b + 256, Qa,  NA, 2, 256,  1920 };
    P.n = 4;
    gemm_seg<<<2080, 256, 0, stream>>>(P);

    // ---- per-node online softmax + aggregation ----
    node_aggr<<<NP + NA / 2, 128, 0, stream>>>(
        Qp, Qa, Yhp, Yha, cnt0, sr0, sr1, sr2, rel_pri, MUb);

    // ---- fused output linear + skip + LayerNorm (64x256 tiles, 470 blocks) ----
    float* out = (float*)d_out;
    OSeg o0 = { MUb,                      a_b,       out,                      Xtp, NP, 0,   0 };
    OSeg o1 = { MUb + (size_t)NP * 256,   a_b + 256, out + (size_t)NP * 256,   Xta, NA, 313, 1 };
    gemm_out_ln<<<470, 256, 0, stream>>>(o0, o1, WT_a0, WT_a1, skip, ln_s, ln_b);
}

// Round 19
// 146.958 us; speedup vs baseline: 1.0421x; 1.0421x over previous
//
#include <hip/hip_runtime.h>
#include <hip/hip_bf16.h>
#include <cstdint>
#include <cstddef>

#define NP 20000
#define NA 10000
#define NEDGE 100000
#define NEG_INF (-__builtin_huge_valf())
#define INV_SQRT_DK 0.17677669529663687f
#define NPPAD 20096
#define NAPAD 10112
#define GEB 391            // ceil(NEDGE/256)
#define MAXDEG 64

typedef __bf16 bf16_t;
typedef __attribute__((ext_vector_type(8))) short s16x8;
typedef __attribute__((ext_vector_type(4))) float f32x4;
typedef __attribute__((ext_vector_type(4))) __bf16 bf16x4;
typedef __attribute__((ext_vector_type(8))) __bf16 bf16x8v;

union B16 { uint4 u; s16x8 s; bf16x8v b; };

typedef const __attribute__((address_space(1))) void* gas1p;
typedef __attribute__((address_space(3))) void* las3p;
#define GLD16(g, l) __builtin_amdgcn_global_load_lds((gas1p)(g), (las3p)(l), 16, 0, 0)

// ---------- prelude: f2b x4 + weight prep x10 + one-pass bucket scatter ----------
__global__ __launch_bounds__(256) void prelude(
    const float* __restrict__ h_paper, const float* __restrict__ h_author,
    const float* __restrict__ t_paper, const float* __restrict__ t_author,
    bf16_t* __restrict__ Xhp, bf16_t* __restrict__ Xha,
    bf16_t* __restrict__ Xtp, bf16_t* __restrict__ Xta,
    const float* __restrict__ k_w, const float* __restrict__ k_b,
    const float* __restrict__ v_w, const float* __restrict__ v_b,
    const float* __restrict__ q_w, const float* __restrict__ a_w,
    const float* __restrict__ rel_att, const float* __restrict__ rel_msg,
    bf16_t* __restrict__ WT_hp, float* __restrict__ Bhp,
    bf16_t* __restrict__ WT_ha, float* __restrict__ Bha,
    bf16_t* __restrict__ WT_q0, bf16_t* __restrict__ WT_q1,
    bf16_t* __restrict__ WT_a0, bf16_t* __restrict__ WT_a1,
    const int* __restrict__ src0, const int* __restrict__ dst0,
    const int* __restrict__ src1, const int* __restrict__ dst1,
    const int* __restrict__ src2, const int* __restrict__ dst2,
    int* __restrict__ cnt,
    int* __restrict__ sr0, int* __restrict__ sr1, int* __restrict__ sr2)
{
    const int b = blockIdx.x;
    const int t = threadIdx.x;
    if (b < 7500) {
        const float* s; bf16_t* d; int n; int bb;
        if (b < 2500)      { s = h_paper;  d = Xhp; n = NP * 32; bb = b; }
        else if (b < 3750) { s = h_author; d = Xha; n = NA * 32; bb = b - 2500; }
        else if (b < 6250) { s = t_paper;  d = Xtp; n = NP * 32; bb = b - 3750; }
        else               { s = t_author; d = Xta; n = NA * 32; bb = b - 6250; }
        int i = bb * 256 + t;
        if (i >= n) return;
        const float* sp = s + (size_t)i * 8;
        float4 x0 = *(const float4*)sp;
        float4 x1 = *(const float4*)(sp + 4);
        B16 o;
        o.b[0] = (__bf16)x0.x; o.b[1] = (__bf16)x0.y; o.b[2] = (__bf16)x0.z; o.b[3] = (__bf16)x0.w;
        o.b[4] = (__bf16)x1.x; o.b[5] = (__bf16)x1.y; o.b[6] = (__bf16)x1.z; o.b[7] = (__bf16)x1.w;
        *(uint4*)(d + (size_t)i * 8) = o.u;
        return;
    }
    if (b >= 10060) {
        const int cb = b - 10060;
        const int et = cb / GEB, bb = cb % GEB;
        const int e = bb * 256 + t;
        if (e >= NEDGE) return;
        const int *src, *dst; int *c, *srs;
        switch (et) {
            case 0: src = src0; dst = dst0; c = cnt;         srs = sr0; break;
            case 1: src = src1; dst = dst1; c = cnt + 20000; srs = sr1; break;
            default: src = src2; dst = dst2; c = cnt + 40000; srs = sr2;
        }
        const int d = dst[e];
        const int pos = atomicAdd(c + d, 1);
        if (pos < MAXDEG) srs[d * MAXDEG + pos] = src[e];
        return;
    }
    const int j = (b - 7500) >> 8;       // weight job 0..9
    const int c = (b - 7500) & 255;      // output column
    if (j < 6) {
        const float *W, *bi, *R; bf16_t* WT; float* bias; int off, kv;
        switch (j) {
            case 0: W = k_w;         bi = k_b;       R = rel_att + 8192;  WT = WT_hp; bias = Bhp; off = 0;   kv = 0; break;
            case 1: W = v_w;         bi = v_b;       R = rel_msg + 8192;  WT = WT_hp; bias = Bhp; off = 0;   kv = 4; break;
            case 2: W = k_w;         bi = k_b;       R = rel_att + 16384; WT = WT_hp; bias = Bhp; off = 512; kv = 0; break;
            case 3: W = v_w;         bi = v_b;       R = rel_msg + 16384; WT = WT_hp; bias = Bhp; off = 512; kv = 4; break;
            case 4: W = k_w + 65536; bi = k_b + 256; R = rel_att;         WT = WT_ha; bias = Bha; off = 0;   kv = 0; break;
            default:W = v_w + 65536; bi = v_b + 256; R = rel_msg;         WT = WT_ha; bias = Bha; off = 0;   kv = 4;
        }
        __shared__ float rs[32];
        const int h = c >> 5, e = c & 31;
        if (t < 32) rs[t] = R[(h * 32 + t) * 32 + e];
        __syncthreads();
        float s = 0.f;
#pragma unroll
        for (int d = 0; d < 32; ++d) s += W[t * 256 + h * 32 + d] * rs[d];
        const int newc = off + (c >> 2) * 8 + kv + (c & 3);
        WT[newc * 256 + t] = (bf16_t)s;
        if (t == 0) {
            float sb = 0.f;
#pragma unroll
            for (int d = 0; d < 32; ++d) sb += bi[h * 32 + d] * rs[d];
            bias[newc] = sb;
        }
    } else {
        const float* W; bf16_t* WT;
        switch (j) { case 6: W = q_w; WT = WT_q0; break;
                     case 7: W = q_w + 65536; WT = WT_q1; break;
                     case 8: W = a_w; WT = WT_a0; break;
                     default: W = a_w + 65536; WT = WT_a1; }
        WT[c * 256 + t] = (bf16_t)W[t * 256 + c];
    }
}

// ---------- 128x128-tile segmented bf16 MFMA GEMM (single-buffer, R17 structure) ----------
struct GSeg {
    const bf16_t* X; const bf16_t* WT; const float* bias; void* Y;
    int M, ncb, ldY, blk0;
};
struct GSegs { GSeg s[4]; int n; };

__global__ __launch_bounds__(256) void gemm_seg(GSegs segs)
{
    int si = 0;
#pragma unroll
    for (int i = 1; i < 4; ++i)
        if (i < segs.n && (int)blockIdx.x >= segs.s[i].blk0) si = i;
    const GSeg g = segs.s[si];
    const int lid = blockIdx.x - g.blk0;
    const int nrb = (g.M + 127) >> 7;
    const int c8 = lid & 7;
    const int rest = lid >> 3;
    const int by = rest % g.ncb;
    const int bx = (rest / g.ncb) * 8 + c8;
    if (bx >= nrb) return;
    const int row0 = bx * 128, col0 = by * 128;
    const int M = g.M, ldY = g.ldY;

    __shared__ uint4 As[512];
    __shared__ uint4 Bs[512];
    __shared__ ushort epi[4][16][72];   // wave-private slices: no epilogue barriers needed
    const int t = threadIdx.x;
    const int w = t >> 6, l = t & 63;
    const int wm = w >> 1, wn = w & 1;
    const int lr = l & 15, ks4 = l >> 4;

    const bf16_t* gA[2]; const bf16_t* gB[2];
    uint4* lA[2]; uint4* lB[2];
#pragma unroll
    for (int c = 0; c < 2; ++c) {
        const int idx = w * 128 + c * 64 + l;
        const int r = idx >> 2;
        const int s = (idx & 3) ^ ((r >> 1) & 3);
        gA[c] = g.X  + (size_t)(row0 + r) * 256 + s * 8;
        gB[c] = g.WT + (size_t)(col0 + r) * 256 + s * 8;
        lA[c] = As + w * 128 + c * 64;
        lB[c] = Bs + w * 128 + c * 64;
    }

    f32x4 acc[4][4] = {};
#pragma unroll
    for (int kk = 0; kk < 8; ++kk) {
        if (kk) __syncthreads();
        GLD16(gA[0] + kk * 32, lA[0]);
        GLD16(gB[0] + kk * 32, lB[0]);
        GLD16(gA[1] + kk * 32, lA[1]);
        GLD16(gB[1] + kk * 32, lB[1]);
        __syncthreads();
        B16 af[4], bfr[4];
#pragma unroll
        for (int i = 0; i < 4; ++i) {
            const int ra = wm * 64 + i * 16 + lr;
            af[i].u = As[ra * 4 + (ks4 ^ ((ra >> 1) & 3))];
            const int rb = wn * 64 + i * 16 + lr;
            bfr[i].u = Bs[rb * 4 + (ks4 ^ ((rb >> 1) & 3))];
        }
#pragma unroll
        for (int i = 0; i < 4; ++i)
#pragma unroll
            for (int jn = 0; jn < 4; ++jn)
                acc[i][jn] = __builtin_amdgcn_mfma_f32_16x16x32_bf16(af[i].s, bfr[jn].s, acc[i][jn], 0, 0, 0);
    }

    // epilogue: per-wave LDS transpose, no cross-wave hazards -> barrier-free
    const int er = l >> 2, ec = (l & 3) * 8;
#pragma unroll
    for (int i = 0; i < 4; ++i) {
#pragma unroll
        for (int jn = 0; jn < 4; ++jn) {
            const float bv = g.bias[col0 + wn * 64 + jn * 16 + lr];
#pragma unroll
            for (int r = 0; r < 4; ++r) {
                union { ushort u; __bf16 b; } cv;
                cv.b = (__bf16)(acc[i][jn][r] + bv);
                epi[w][ks4 * 4 + r][jn * 16 + lr] = cv.u;
            }
        }
        const int grow = row0 + wm * 64 + i * 16 + er;
        if (grow < M) {
            uint4 v0 = *(const uint4*)&epi[w][er][ec];
            uint4 v1 = *(const uint4*)&epi[w][er][ec + 32];
            bf16_t* yp = (bf16_t*)g.Y + (size_t)grow * ldY + col0 + wn * 64;
            *(uint4*)(yp + ec) = v0;
            *(uint4*)(yp + ec + 32) = v1;
        }
    }
}

// ---------- fused out-GEMM + skip + LayerNorm: 64x256 tile, 4 waves (R17 structure) ----------
struct OSeg { const bf16_t* X; const float* bias; float* Y; const bf16_t* T; int M, blk0, nt; };

__global__ __launch_bounds__(256) void gemm_out_ln(
    OSeg s0, OSeg s1, const bf16_t* __restrict__ WT0, const bf16_t* __restrict__ WT1,
    const float* __restrict__ skip, const float* __restrict__ lns,
    const float* __restrict__ lnb)
{
    const bool second = (int)blockIdx.x >= s1.blk0;
    const OSeg g = second ? s1 : s0;
    const bf16_t* __restrict__ WT = second ? WT1 : WT0;
    const int row0 = ((int)blockIdx.x - g.blk0) * 64;

    union SM {
        uint4 ab[1280];  // A words [0..255] | B words [256..1279], 20 KB
        struct { ushort epi[4][16][72]; float2 part[16][4]; } e;
    };
    __shared__ SM sm;
    const int t = threadIdx.x;
    const int w = t >> 6, l = t & 63;
    const int lr = l & 15, ks4 = l >> 4;

    const bf16_t* gA; uint4* lA;
    const bf16_t* gB[4]; uint4* lB[4];
    {
        const int idx = w * 64 + l;
        const int r = idx >> 2;
        const int s = (idx & 3) ^ ((r >> 1) & 3);
        gA = g.X + (size_t)(row0 + r) * 256 + s * 8;
        lA = sm.ab + w * 64;
    }
#pragma unroll
    for (int c = 0; c < 4; ++c) {
        const int idx = w * 256 + c * 64 + l;
        const int r = idx >> 2;
        const int s = (idx & 3) ^ ((r >> 1) & 3);
        gB[c] = WT + (size_t)r * 256 + s * 8;
        lB[c] = sm.ab + 256 + w * 256 + c * 64;
    }

    f32x4 acc[4][4] = {};
#pragma unroll
    for (int kk = 0; kk < 8; ++kk) {
        if (kk) __syncthreads();
        GLD16(gA + kk * 32, lA);
        GLD16(gB[0] + kk * 32, lB[0]);
        GLD16(gB[1] + kk * 32, lB[1]);
        GLD16(gB[2] + kk * 32, lB[2]);
        GLD16(gB[3] + kk * 32, lB[3]);
        __syncthreads();
        B16 af[4], bfr[4];
#pragma unroll
        for (int i = 0; i < 4; ++i) {
            const int ra = i * 16 + lr;
            af[i].u = sm.ab[ra * 4 + (ks4 ^ ((ra >> 1) & 3))];
            const int rb = w * 64 + i * 16 + lr;
            bfr[i].u = sm.ab[256 + rb * 4 + (ks4 ^ ((rb >> 1) & 3))];
        }
#pragma unroll
        for (int i = 0; i < 4; ++i)
#pragma unroll
            for (int jn = 0; jn < 4; ++jn)
                acc[i][jn] = __builtin_amdgcn_mfma_f32_16x16x32_bf16(af[i].s, bfr[jn].s, acc[i][jn], 0, 0, 0);
    }
    __syncthreads();  // frag reads done before epi aliases ab

    const float alpha = 1.f / (1.f + __expf(-skip[g.nt]));
    const float beta = 1.f - alpha;
    const int er = l >> 2, cb = (l & 3) * 16;
#pragma unroll
    for (int i = 0; i < 4; ++i) {
#pragma unroll
        for (int jn = 0; jn < 4; ++jn) {
            const float bv = g.bias[w * 64 + jn * 16 + lr];
#pragma unroll
            for (int r = 0; r < 4; ++r) {
                union { ushort u; __bf16 b; } cv;
                cv.b = (__bf16)(acc[i][jn][r] + bv);
                sm.e.epi[w][ks4 * 4 + r][jn * 16 + lr] = cv.u;
            }
        }
        const int grow = row0 + i * 16 + er;
        float v[16];
        {
            const bf16_t* tp = g.T + (size_t)grow * 256 + w * 64 + cb;
            B16 ov0, ov1, tv0, tv1;
            ov0.u = *(const uint4*)&sm.e.epi[w][er][cb];
            ov1.u = *(const uint4*)&sm.e.epi[w][er][cb + 8];
            tv0.u = *(const uint4*)(tp);
            tv1.u = *(const uint4*)(tp + 8);
#pragma unroll
            for (int q = 0; q < 8; ++q) {
                v[q]     = (float)ov0.b[q] * alpha + (float)tv0.b[q] * beta;
                v[8 + q] = (float)ov1.b[q] * alpha + (float)tv1.b[q] * beta;
            }
        }
        float s1 = 0.f, s2 = 0.f;
#pragma unroll
        for (int q = 0; q < 16; ++q) { s1 += v[q]; s2 += v[q] * v[q]; }
        s1 += __shfl_xor(s1, 1, 64); s2 += __shfl_xor(s2, 1, 64);
        s1 += __shfl_xor(s1, 2, 64); s2 += __shfl_xor(s2, 2, 64);
        if ((l & 3) == 0) sm.e.part[er][w] = make_float2(s1, s2);
        __syncthreads();   // cross-wave part[] reduction
        float ts1 = 0.f, ts2 = 0.f;
#pragma unroll
        for (int q = 0; q < 4; ++q) { float2 p = sm.e.part[er][q]; ts1 += p.x; ts2 += p.y; }
        const float mean = ts1 * (1.f / 256.f);
        const float var = ts2 * (1.f / 256.f) - mean * mean;
        const float rstd = rsqrtf(var + 1e-5f);
        if (grow < g.M) {
            const int colb = w * 64 + cb;
            const float* ls = lns + g.nt * 256 + colb;
            const float* lb = lnb + g.nt * 256 + colb;
            float* op = g.Y + (size_t)grow * 256 + colb;
#pragma unroll
            for (int q = 0; q < 16; q += 4) {
                float4 o4;
                o4.x = (v[q + 0] - mean) * rstd * ls[q + 0] + lb[q + 0];
                o4.y = (v[q + 1] - mean) * rstd * ls[q + 1] + lb[q + 1];
                o4.z = (v[q + 2] - mean) * rstd * ls[q + 2] + lb[q + 2];
                o4.w = (v[q + 3] - mean) * rstd * ls[q + 3] + lb[q + 3];
                *(float4*)(op + q) = o4;
            }
        }
        __syncthreads();   // part[] reuse hazard for next i
    }
}

// ---------- per-node online-softmax aggregation (bucketed lists, wave per list) ----------
__device__ __forceinline__ float4 ldb4(const bf16_t* p) {
    bf16x4 v = *(const bf16x4*)p;
    return make_float4((float)v[0], (float)v[1], (float)v[2], (float)v[3]);
}

__device__ __forceinline__ void upd(float& m, float& den, float4& acc,
                                    float score, const float4& v) {
    const float nm = fmaxf(m, score);
    const float r = __expf(m - nm);
    const float p = __expf(score - nm);
    den = den * r + p;
    acc.x = acc.x * r + v.x * p;
    acc.y = acc.y * r + v.y * p;
    acc.z = acc.z * r + v.z * p;
    acc.w = acc.w * r + v.w * p;
    m = nm;
}

__device__ __forceinline__ void step_kv(float& m, float& den, float4& acc,
                                        uint4 kvu, float scale, const float4& q) {
    B16 kv; kv.u = kvu;
    float d = q.x * (float)kv.b[0] + q.y * (float)kv.b[1]
            + q.z * (float)kv.b[2] + q.w * (float)kv.b[3];
    d += __shfl_xor(d, 1, 64);
    d += __shfl_xor(d, 2, 64);
    d += __shfl_xor(d, 4, 64);
    const float4 v = make_float4((float)kv.b[4], (float)kv.b[5],
                                 (float)kv.b[6], (float)kv.b[7]);
    upd(m, den, acc, d * scale, v);
}

__device__ __forceinline__ void aggr_chain(
    const bf16_t* __restrict__ KV, int ld,
    const int* __restrict__ srcs, int deg,
    float scaleH, int lane, const float4& q, float4& res)
{
    res = make_float4(0.f, 0.f, 0.f, 0.f);
    if (deg <= 0) return;
    float m = NEG_INF, den = 0.f;
    float4 acc = make_float4(0.f, 0.f, 0.f, 0.f);
    uint4 kv0 = *(const uint4*)(KV + (size_t)srcs[0] * ld + lane * 8);
    uint4 kv1 = (1 < deg) ? *(const uint4*)(KV + (size_t)srcs[1] * ld + lane * 8) : kv0;
    for (int i = 0; i < deg; ++i) {
        uint4 nx = (i + 2 < deg) ? *(const uint4*)(KV + (size_t)srcs[i + 2] * ld + lane * 8) : kv1;
        step_kv(m, den, acc, kv0, scaleH, q);
        kv0 = kv1; kv1 = nx;
    }
    const float inv = 1.f / den;
    res = make_float4(acc.x * inv, acc.y * inv, acc.z * inv, acc.w * inv);
}

__global__ __launch_bounds__(128) void node_aggr(
    const bf16_t* __restrict__ Qp, const bf16_t* __restrict__ Qa,
    const bf16_t* __restrict__ Yhp, const bf16_t* __restrict__ Yha,
    const int* __restrict__ cnt,
    const int* __restrict__ sr0, const int* __restrict__ sr1, const int* __restrict__ sr2,
    const float* __restrict__ rel_pri, bf16_t* __restrict__ MUb)
{
    __shared__ float4 part[64];
    const int t = threadIdx.x;
    const int wv = t >> 6, lane = t & 63;
    const int h = lane >> 3;
    const int b = blockIdx.x;
    if (b < NP) {
        const int node = b;
        const float4 q = ldb4(Qp + (size_t)node * 256 + lane * 4);
        float4 res;
        if (wv == 0)
            aggr_chain(Yha, 512,  sr0 + (size_t)node * MAXDEG, cnt[node],
                       rel_pri[h] * INV_SQRT_DK, lane, q, res);
        else
            aggr_chain(Yhp, 1024, sr1 + (size_t)node * MAXDEG, cnt[20000 + node],
                       rel_pri[8 + h] * INV_SQRT_DK, lane, q, res);
        if (wv == 1) part[lane] = res;
        __syncthreads();
        if (wv == 0) {
            const float4 c = part[lane];
            bf16x4 o;
            o[0] = (__bf16)((res.x + c.x) * 0.5f);
            o[1] = (__bf16)((res.y + c.y) * 0.5f);
            o[2] = (__bf16)((res.z + c.z) * 0.5f);
            o[3] = (__bf16)((res.w + c.w) * 0.5f);
            *(bf16x4*)(MUb + (size_t)node * 256 + lane * 4) = o;
        }
    } else {
        const int node2 = (b - NP) * 2 + wv;   // author index
        if (node2 >= NA) return;
        const float4 q = ldb4(Qa + (size_t)node2 * 256 + lane * 4);
        float4 res;
        aggr_chain(Yhp + 512, 1024, sr2 + (size_t)node2 * MAXDEG, cnt[40000 + node2],
                   rel_pri[16 + h] * INV_SQRT_DK, lane, q, res);
        bf16x4 o;
        o[0] = (__bf16)res.x; o[1] = (__bf16)res.y;
        o[2] = (__bf16)res.z; o[3] = (__bf16)res.w;
        *(bf16x4*)(MUb + (size_t)(NP + node2) * 256 + lane * 4) = o;
    }
}

extern "C" void kernel_launch(void* const* d_in, const int* in_sizes, int n_in,
                              void* d_out, int out_size, void* d_ws, size_t ws_size,
                              hipStream_t stream) {
    const float* h_paper  = (const float*)d_in[0];
    const float* h_author = (const float*)d_in[1];
    const float* t_paper  = (const float*)d_in[2];
    const float* t_author = (const float*)d_in[3];
    const float* k_w = (const float*)d_in[4];
    const float* k_b = (const float*)d_in[5];
    const float* q_w = (const float*)d_in[6];
    const float* q_b = (const float*)d_in[7];
    const float* v_w = (const float*)d_in[8];
    const float* v_b = (const float*)d_in[9];
    const float* a_w = (const float*)d_in[10];
    const float* a_b = (const float*)d_in[11];
    const float* rel_pri = (const float*)d_in[12];
    const float* rel_att = (const float*)d_in[13];
    const float* rel_msg = (const float*)d_in[14];
    const float* skip = (const float*)d_in[15];
    const float* ln_s = (const float*)d_in[16];
    const float* ln_b = (const float*)d_in[17];
    const int* src0 = (const int*)d_in[18];
    const int* dst0 = (const int*)d_in[19];
    const int* src1 = (const int*)d_in[20];
    const int* dst1 = (const int*)d_in[21];
    const int* src2 = (const int*)d_in[22];
    const int* dst2 = (const int*)d_in[23];

    // ---- workspace layout ----
    char* base = (char*)d_ws;
    size_t off = 0;
    auto alloc = [&](size_t bytes) { char* p = base + off; off += (bytes + 255) & ~(size_t)255; return p; };
    bf16_t* Xhp  = (bf16_t*)alloc((size_t)NPPAD * 256 * 2);
    bf16_t* Xha  = (bf16_t*)alloc((size_t)NAPAD * 256 * 2);
    bf16_t* Xtp  = (bf16_t*)alloc((size_t)NPPAD * 256 * 2);
    bf16_t* Xta  = (bf16_t*)alloc((size_t)NAPAD * 256 * 2);
    bf16_t* Yhp  = (bf16_t*)alloc((size_t)NP * 1024 * 2);  // [KV1 | KV2] interleaved
    bf16_t* Yha  = (bf16_t*)alloc((size_t)NA * 512 * 2);   // [KV0] interleaved
    bf16_t* Qp   = (bf16_t*)alloc((size_t)NP * 256 * 2);
    bf16_t* Qa   = (bf16_t*)alloc((size_t)NA * 256 * 2);
    bf16_t* MUb  = (bf16_t*)alloc((size_t)(NP + NAPAD) * 256 * 2);
    bf16_t* WT_hp = (bf16_t*)alloc(1024 * 256 * 2);
    bf16_t* WT_ha = (bf16_t*)alloc(512 * 256 * 2);
    bf16_t* WT_q0 = (bf16_t*)alloc(256 * 256 * 2);
    bf16_t* WT_q1 = (bf16_t*)alloc(256 * 256 * 2);
    bf16_t* WT_a0 = (bf16_t*)alloc(256 * 256 * 2);
    bf16_t* WT_a1 = (bf16_t*)alloc(256 * 256 * 2);
    float* Bhp = (float*)alloc(1024 * 4);
    float* Bha = (float*)alloc(512 * 4);
    int* cnt0 = (int*)alloc(50000 * 4);   // cnt0[20000] | cnt1[20000] | cnt2[10000]
    int* sr0 = (int*)alloc((size_t)NP * MAXDEG * 4);
    int* sr1 = (int*)alloc((size_t)NP * MAXDEG * 4);
    int* sr2 = (int*)alloc((size_t)NA * MAXDEG * 4);

    // ---- zero counts (async memset, graph-capture legal) ----
    hipMemsetAsync(cnt0, 0, 50000 * sizeof(int), stream);

    // ---- prelude: f2b + weight prep + one-pass bucket scatter ----
    prelude<<<10060 + 3 * GEB, 256, 0, stream>>>(
        h_paper, h_author, t_paper, t_author, Xhp, Xha, Xtp, Xta,
        k_w, k_b, v_w, v_b, q_w, a_w, rel_att, rel_msg,
        WT_hp, Bhp, WT_ha, Bha, WT_q0, WT_q1, WT_a0, WT_a1,
        src0, dst0, src1, dst1, src2, dst2, cnt0, sr0, sr1, sr2);

    // ---- projections (4 segments, XCD-pinned col-tiles) ----
    GSegs P{};
    P.s[0] = { Xhp, WT_hp, Bhp,       Yhp, NP, 8, 1024, 0 };
    P.s[1] = { Xha, WT_ha, Bha,       Yha, NA, 4, 512,  1280 };
    P.s[2] = { Xtp, WT_q0, q_b,       Qp,  NP, 2, 256,  1600 };
    P.s[3] = { Xta, WT_q1, q_b + 256, Qa,  NA, 2, 256,  1920 };
    P.n = 4;
    gemm_seg<<<2080, 256, 0, stream>>>(P);

    // ---- per-node online softmax + aggregation ----
    node_aggr<<<NP + NA / 2, 128, 0, stream>>>(
        Qp, Qa, Yhp, Yha, cnt0, sr0, sr1, sr2, rel_pri, MUb);

    // ---- fused output linear + skip + LayerNorm (64x256 tiles, 470 blocks) ----
    float* out = (float*)d_out;
    OSeg o0 = { MUb,                      a_b,       out,                      Xtp, NP, 0,   0 };
    OSeg o1 = { MUb + (size_t)NP * 256,   a_b + 256, out + (size_t)NP * 256,   Xta, NA, 313, 1 };
    gemm_out_ln<<<470, 256, 0, stream>>>(o0, o1, WT_a0, WT_a1, skip, ln_s, ln_b);
}